// Round 14
// baseline (657.312 us; speedup 1.0000x reference)
//
#include <hip/hip_runtime.h>

// GCN forward, fused layer kernel v2.
// Per layer: gather H' rows -> LDS M-tile (128 nodes) -> MFMA M@(Whi+Wlo) with a
// SINGLE accumulator (Wlo stored unscaled fp16; subnormal contribution negligible)
// -> epilogue relu/scale -> H'next (or in-LDS decoder on last layer).
// No W staging in LDS (L1/L2-resident); 32KB LDS; launch_bounds(512,6) for occupancy.

typedef float f32x4 __attribute__((ext_vector_type(4)));
typedef _Float16 h8 __attribute__((ext_vector_type(8)));

#define BKT_CAP 6144

// ---------------- CSR build (bucketed) ----------------

__global__ __launch_bounds__(256) void k_bin(const int* __restrict__ src, const int* __restrict__ dst,
                                             int* __restrict__ bcnt, unsigned* __restrict__ ebuf, int E, int NB) {
  __shared__ int hist[512];
  __shared__ int lofs[512];
  int tid = threadIdx.x;
  int base = blockIdx.x * 4096;
  for (int i = tid; i < NB; i += 256) hist[i] = 0;
  __syncthreads();
  unsigned rec[16];
  int bk[16];
#pragma unroll
  for (int j = 0; j < 16; j++) {
    int e = base + j * 256 + tid;
    bk[j] = -1;
    if (e < E) {
      int d = dst[e];
      rec[j] = ((unsigned)(d & 255) << 24) | (unsigned)src[e];
      bk[j] = d >> 8;
      atomicAdd(&hist[bk[j]], 1);
    }
  }
  __syncthreads();
  for (int i = tid; i < NB; i += 256) {
    int c = hist[i];
    lofs[i] = c ? atomicAdd(&bcnt[i], c) : 0;
    hist[i] = 0;
  }
  __syncthreads();
#pragma unroll
  for (int j = 0; j < 16; j++) {
    if (bk[j] >= 0) {
      int p = lofs[bk[j]] + atomicAdd(&hist[bk[j]], 1);
      if (p < BKT_CAP) ebuf[(size_t)bk[j] * BKT_CAP + p] = rec[j];
    }
  }
}

__global__ __launch_bounds__(512) void k_bscan(const int* __restrict__ bcnt, int* __restrict__ bbase,
                                               int* __restrict__ rp, int NB, int N, int E) {
  __shared__ int wsum[8];
  int tid = threadIdx.x;
  int v = (tid < NB) ? bcnt[tid] : 0;
  int l = tid & 63, w = tid >> 6;
  int s = v;
#pragma unroll
  for (int off = 1; off < 64; off <<= 1) { int t = __shfl_up(s, off); if (l >= off) s += t; }
  if (l == 63) wsum[w] = s;
  __syncthreads();
  int woff = 0;
  for (int i = 0; i < w; i++) woff += wsum[i];
  if (tid < NB) bbase[tid] = woff + s - v;
  if (tid == 0) rp[N] = E;
}

__global__ __launch_bounds__(256) void k_bfill(const unsigned* __restrict__ ebuf, const int* __restrict__ bcnt,
                                               const int* __restrict__ bbase, int* __restrict__ rp,
                                               float* __restrict__ dinv, int* __restrict__ col, int N) {
  __shared__ int h[256];
  __shared__ int wsum[4];
  int b = blockIdx.x, tid = threadIdx.x;
  h[tid] = 0;
  __syncthreads();
  int n = min(bcnt[b], BKT_CAP);
  int bb = bbase[b];
  const unsigned* eb = ebuf + (size_t)b * BKT_CAP;
  for (int i = tid; i < n; i += 256) atomicAdd(&h[eb[i] >> 24], 1);
  __syncthreads();
  int cntv = h[tid];
  int l = tid & 63, wv = tid >> 6;
  int s = cntv;
#pragma unroll
  for (int off = 1; off < 64; off <<= 1) { int t = __shfl_up(s, off); if (l >= off) s += t; }
  if (l == 63) wsum[wv] = s;
  __syncthreads();
  int woff = 0;
  for (int i = 0; i < wv; i++) woff += wsum[i];
  int lpre = woff + s - cntv;
  int d = (b << 8) + tid;
  if (d < N) {
    rp[d] = bb + lpre;
    dinv[d] = 1.0f / sqrtf((float)(cntv + 1));
  }
  __syncthreads();
  h[tid] = lpre;
  __syncthreads();
  for (int i = tid; i < n; i += 256) {
    unsigned r = eb[i];
    int dlow = r >> 24;
    int pos = bb + atomicAdd(&h[dlow], 1);
    col[pos] = (int)(r & 0xFFFFFFu);
  }
}

// convW [L][k][c] -> transposed fp16 planes [L][c][k]; Wlo UNSCALED residual.
__global__ __launch_bounds__(128) void k_prep_w(const float* __restrict__ convW, _Float16* __restrict__ Whi,
                                                _Float16* __restrict__ Wlo) {
  int lk = blockIdx.x;
  int l = lk >> 7, k = lk & 127, c = threadIdx.x;
  float x = convW[((size_t)l * 128 + k) * 128 + c];
  _Float16 hi = (_Float16)x;
  _Float16 lo = (_Float16)(x - (float)hi);
  size_t o = ((size_t)l * 128 + c) * 128 + k;
  Whi[o] = hi;
  Wlo[o] = lo;
}

// H'[i][c] = dinv[i] * relu(x[i] @ encW + encb)
__global__ __launch_bounds__(256) void k_encoder(const float* __restrict__ x, const float* __restrict__ W,
                                                 const float* __restrict__ b, const float* __restrict__ dinv,
                                                 _Float16* __restrict__ Hp, int N) {
  int node = blockIdx.x * 2 + (threadIdx.x >> 7);
  int c = threadIdx.x & 127;
  if (node >= N) return;
  const float* xr = x + (size_t)node * 16;
  float acc = b[c];
#pragma unroll
  for (int k = 0; k < 16; k++) acc = fmaf(xr[k], W[k * 128 + c], acc);
  Hp[(size_t)node * 128 + c] = (_Float16)(dinv[node] * fmaxf(acc, 0.0f));
}

// ---------------- fused layer ----------------
__global__ __launch_bounds__(512, 6) void k_layer(const _Float16* __restrict__ Hp, const int* __restrict__ rp,
                                                  const int* __restrict__ col, const float* __restrict__ dinv,
                                                  const _Float16* __restrict__ Whi, const _Float16* __restrict__ Wlo,
                                                  const float* __restrict__ bias, _Float16* __restrict__ Hn,
                                                  const float* __restrict__ decW, const float* __restrict__ decb,
                                                  float* __restrict__ out, int last, int N) {
  __shared__ __align__(16) ushort ldsM[128 * 128];  // 32 KB: 128 rows x 256B, XOR-swizzled
  char* mB = reinterpret_cast<char*>(ldsM);
  const int tid = threadIdx.x;
  const int row0 = blockIdx.x * 128;

  // ---- Phase 1: gather. 32 groups of 16 lanes; group owns 4 nodes (full row each).
  {
    int grp = tid >> 4, ln = tid & 15;
#pragma unroll
    for (int t = 0; t < 4; t++) {
      int lrow = grp * 4 + t;
      int d = row0 + lrow;
      int moff = (lrow * 256 + ln * 16) ^ ((lrow & 7) << 4);
      h8 z = {(_Float16)0, (_Float16)0, (_Float16)0, (_Float16)0,
              (_Float16)0, (_Float16)0, (_Float16)0, (_Float16)0};
      if (d < N) {
        h8 a0 = z, a1 = z, a2 = z, a3 = z;
        a0 += *reinterpret_cast<const h8*>(Hp + (size_t)d * 128 + ln * 8);  // self
        int e0 = rp[d], e1 = rp[d + 1];
        int i = e0;
        for (; i + 3 < e1; i += 4) {
          int s0 = col[i], s1 = col[i + 1], s2 = col[i + 2], s3 = col[i + 3];
          a0 += *reinterpret_cast<const h8*>(Hp + (size_t)s0 * 128 + ln * 8);
          a1 += *reinterpret_cast<const h8*>(Hp + (size_t)s1 * 128 + ln * 8);
          a2 += *reinterpret_cast<const h8*>(Hp + (size_t)s2 * 128 + ln * 8);
          a3 += *reinterpret_cast<const h8*>(Hp + (size_t)s3 * 128 + ln * 8);
        }
        if (i < e1)     a1 += *reinterpret_cast<const h8*>(Hp + (size_t)col[i] * 128 + ln * 8);
        if (i + 1 < e1) a2 += *reinterpret_cast<const h8*>(Hp + (size_t)col[i + 1] * 128 + ln * 8);
        if (i + 2 < e1) a3 += *reinterpret_cast<const h8*>(Hp + (size_t)col[i + 2] * 128 + ln * 8);
        h8 m;
#pragma unroll
        for (int j = 0; j < 8; j++) {
          float f = ((float)a0[j] + (float)a1[j]) + ((float)a2[j] + (float)a3[j]);
          m[j] = (_Float16)f;
        }
        *reinterpret_cast<h8*>(mB + moff) = m;
      } else {
        *reinterpret_cast<h8*>(mB + moff) = z;
      }
    }
  }
  __syncthreads();

  // ---- Phase 2: M @ (Whi + Wlo), single accumulator, W fragments straight from L1/L2.
  const int w = tid >> 6, l = tid & 63;
  const int wm = w >> 1, wn = w & 1;
  const int lr = l & 15, lg = l >> 4;
  f32x4 zero4 = {0.0f, 0.0f, 0.0f, 0.0f};
  f32x4 acc[2][4];
#pragma unroll
  for (int m = 0; m < 2; m++)
#pragma unroll
    for (int n = 0; n < 4; n++) acc[m][n] = zero4;

#pragma unroll
  for (int half = 0; half < 2; half++) {
#pragma unroll
    for (int ksl = 0; ksl < 2; ksl++) {
      int ko = half * 64 + ksl * 32 + lg * 8;   // element offset in 128-K row
      h8 ah[2];
#pragma unroll
      for (int m = 0; m < 2; m++) {
        int row = wm * 32 + m * 16 + lr;
        ah[m] = *reinterpret_cast<const h8*>(mB + ((row * 256 + ko * 2) ^ ((row & 7) << 4)));
      }
#pragma unroll
      for (int n = 0; n < 4; n++) {
        int colr = wn * 64 + n * 16 + lr;
        h8 wh = *reinterpret_cast<const h8*>(Whi + (size_t)colr * 128 + ko);
        h8 wl = *reinterpret_cast<const h8*>(Wlo + (size_t)colr * 128 + ko);
#pragma unroll
        for (int m = 0; m < 2; m++)
          acc[m][n] = __builtin_amdgcn_mfma_f32_16x16x32_f16(ah[m], wh, acc[m][n], 0, 0, 0);
#pragma unroll
        for (int m = 0; m < 2; m++)
          acc[m][n] = __builtin_amdgcn_mfma_f32_16x16x32_f16(ah[m], wl, acc[m][n], 0, 0, 0);
      }
    }
  }

  // ---- Epilogue
  if (last) __syncthreads();  // all ldsM reads done before reuse
#pragma unroll
  for (int m = 0; m < 2; m++) {
    int lbase = wm * 32 + m * 16 + lg * 4;
#pragma unroll
    for (int r = 0; r < 4; r++) {
      int lrow = lbase + r;
      int grow = row0 + lrow;
      if (grow < N) {
        float dv = dinv[grow];
#pragma unroll
        for (int n = 0; n < 4; n++) {
          int colc = wn * 64 + n * 16 + lr;
          float h = fmaxf(fmaf(dv, acc[m][n][r], bias[colc]), 0.0f);
          if (!last) {
            Hn[(size_t)grow * 128 + colc] = (_Float16)(dv * h);
          } else {
            _Float16 hf = (_Float16)h;
            *reinterpret_cast<ushort*>(mB + ((lrow * 256 + colc * 2) ^ ((lrow & 7) << 4))) =
                *reinterpret_cast<ushort*>(&hf);
          }
        }
      }
    }
  }

  if (last) {
    __syncthreads();
    int grp = tid >> 4, ln = tid & 15;
#pragma unroll
    for (int t = 0; t < 4; t++) {
      int lrow = grp * 4 + t;
      int d = row0 + lrow;
      if (d < N) {
        h8 hv = *reinterpret_cast<const h8*>(mB + ((lrow * 256 + ln * 16) ^ ((lrow & 7) << 4)));
        float p0 = 0.f, p1 = 0.f, p2 = 0.f;
#pragma unroll
        for (int j = 0; j < 8; j++) {
          int c = ln * 8 + j;
          float o = (float)hv[j];
          p0 = fmaf(o, decW[c * 3 + 0], p0);
          p1 = fmaf(o, decW[c * 3 + 1], p1);
          p2 = fmaf(o, decW[c * 3 + 2], p2);
        }
#pragma unroll
        for (int off = 8; off > 0; off >>= 1) {
          p0 += __shfl_xor(p0, off);
          p1 += __shfl_xor(p1, off);
          p2 += __shfl_xor(p2, off);
        }
        if (ln == 0) {
          out[(size_t)d * 3 + 0] = p0 + decb[0];
          out[(size_t)d * 3 + 1] = p1 + decb[1];
          out[(size_t)d * 3 + 2] = p2 + decb[2];
        }
      }
    }
  }
}

extern "C" void kernel_launch(void* const* d_in, const int* in_sizes, int n_in,
                              void* d_out, int out_size, void* d_ws, size_t ws_size,
                              hipStream_t stream) {
  const float* x     = (const float*)d_in[0];
  const int*   ei    = (const int*)d_in[1];
  const float* encW  = (const float*)d_in[2];
  const float* encb  = (const float*)d_in[3];
  const float* convW = (const float*)d_in[4];
  const float* convb = (const float*)d_in[5];
  const float* decW  = (const float*)d_in[6];
  const float* decb  = (const float*)d_in[7];
  const int N = in_sizes[0] / 16;
  const int E = in_sizes[1] / 2;
  const int L = in_sizes[4] / (128 * 128);
  const int* src = ei;
  const int* dst = ei + E;
  const int NB = (N + 255) >> 8;

  char* p = (char*)d_ws;
  auto alloc = [&](size_t bytes) -> void* {
    void* q = (void*)p;
    p += (bytes + 255) & ~(size_t)255;
    return q;
  };
  int*       rp     = (int*)alloc((size_t)(N + 1) * 4);
  int*       bcnt   = (int*)alloc((size_t)NB * 4);
  int*       bbase  = (int*)alloc((size_t)NB * 4);
  float*     dinv   = (float*)alloc((size_t)N * 4);
  int*       colA   = (int*)alloc((size_t)E * 4);
  _Float16*  HA     = (_Float16*)alloc((size_t)N * 128 * 2);
  // HB aliases ebuf (ebuf dead after k_bfill; HB first written by layer 0).
  size_t hb_bytes   = (size_t)N * 128 * 2;
  size_t ebuf_bytes = (size_t)NB * BKT_CAP * 4;
  void*  hb_union   = alloc(hb_bytes > ebuf_bytes ? hb_bytes : ebuf_bytes);
  _Float16* HB      = (_Float16*)hb_union;
  unsigned* ebuf    = (unsigned*)hb_union;
  _Float16*  Whi    = (_Float16*)alloc((size_t)L * 128 * 128 * 2);
  _Float16*  Wlo    = (_Float16*)alloc((size_t)L * 128 * 128 * 2);

  hipMemsetAsync(bcnt, 0, (size_t)NB * 4, stream);
  k_bin<<<(E + 4095) / 4096, 256, 0, stream>>>(src, dst, bcnt, ebuf, E, NB);
  k_bscan<<<1, 512, 0, stream>>>(bcnt, bbase, rp, NB, N, E);
  k_bfill<<<NB, 256, 0, stream>>>(ebuf, bcnt, bbase, rp, dinv, colA, N);
  k_prep_w<<<L * 128, 128, 0, stream>>>(convW, Whi, Wlo);
  k_encoder<<<(N + 1) / 2, 256, 0, stream>>>(x, encW, encb, dinv, HA, N);
  int gblocks = (N + 127) / 128;
  _Float16* Hp = HA;
  _Float16* Hn = HB;
  for (int l = 0; l < L; l++) {
    int last = (l == L - 1) ? 1 : 0;
    k_layer<<<gblocks, 512, 0, stream>>>(Hp, rp, colA, dinv, Whi + (size_t)l * 128 * 128,
                                         Wlo + (size_t)l * 128 * 128, convb + l * 128, Hn,
                                         decW, decb, (float*)d_out, last, N);
    _Float16* t = Hp; Hp = Hn; Hn = t;
  }
}

// Round 15
// 581.680 us; speedup vs baseline: 1.1300x; 1.1300x over previous
//
#include <hip/hip_runtime.h>

// GCN forward, fused layer kernel v3.
// Per layer: gather H' rows -> LDS M-tile (128 nodes) -> MFMA M@(Whi+Wlo), W staged
// in a 16KB LDS plane buffer (v1), SINGLE accumulator via unscaled fp16 Wlo residual
// (v2, verified absmax-neutral) -> epilogue relu/scale -> H'next (last: in-LDS decoder).
// launch_bounds(512,6): 3 blocks/CU, 24 waves/CU for the gather phase.

typedef float f32x4 __attribute__((ext_vector_type(4)));
typedef _Float16 h8 __attribute__((ext_vector_type(8)));

#define BKT_CAP 6144

// ---------------- CSR build (bucketed) ----------------

__global__ __launch_bounds__(256) void k_bin(const int* __restrict__ src, const int* __restrict__ dst,
                                             int* __restrict__ bcnt, unsigned* __restrict__ ebuf, int E, int NB) {
  __shared__ int hist[512];
  __shared__ int lofs[512];
  int tid = threadIdx.x;
  int base = blockIdx.x * 4096;
  for (int i = tid; i < NB; i += 256) hist[i] = 0;
  __syncthreads();
  unsigned rec[16];
  int bk[16];
#pragma unroll
  for (int j = 0; j < 16; j++) {
    int e = base + j * 256 + tid;
    bk[j] = -1;
    if (e < E) {
      int d = dst[e];
      rec[j] = ((unsigned)(d & 255) << 24) | (unsigned)src[e];
      bk[j] = d >> 8;
      atomicAdd(&hist[bk[j]], 1);
    }
  }
  __syncthreads();
  for (int i = tid; i < NB; i += 256) {
    int c = hist[i];
    lofs[i] = c ? atomicAdd(&bcnt[i], c) : 0;
    hist[i] = 0;
  }
  __syncthreads();
#pragma unroll
  for (int j = 0; j < 16; j++) {
    if (bk[j] >= 0) {
      int p = lofs[bk[j]] + atomicAdd(&hist[bk[j]], 1);
      if (p < BKT_CAP) ebuf[(size_t)bk[j] * BKT_CAP + p] = rec[j];
    }
  }
}

__global__ __launch_bounds__(512) void k_bscan(const int* __restrict__ bcnt, int* __restrict__ bbase,
                                               int* __restrict__ rp, int NB, int N, int E) {
  __shared__ int wsum[8];
  int tid = threadIdx.x;
  int v = (tid < NB) ? bcnt[tid] : 0;
  int l = tid & 63, w = tid >> 6;
  int s = v;
#pragma unroll
  for (int off = 1; off < 64; off <<= 1) { int t = __shfl_up(s, off); if (l >= off) s += t; }
  if (l == 63) wsum[w] = s;
  __syncthreads();
  int woff = 0;
  for (int i = 0; i < w; i++) woff += wsum[i];
  if (tid < NB) bbase[tid] = woff + s - v;
  if (tid == 0) rp[N] = E;
}

__global__ __launch_bounds__(256) void k_bfill(const unsigned* __restrict__ ebuf, const int* __restrict__ bcnt,
                                               const int* __restrict__ bbase, int* __restrict__ rp,
                                               float* __restrict__ dinv, int* __restrict__ col, int N) {
  __shared__ int h[256];
  __shared__ int wsum[4];
  int b = blockIdx.x, tid = threadIdx.x;
  h[tid] = 0;
  __syncthreads();
  int n = min(bcnt[b], BKT_CAP);
  int bb = bbase[b];
  const unsigned* eb = ebuf + (size_t)b * BKT_CAP;
  for (int i = tid; i < n; i += 256) atomicAdd(&h[eb[i] >> 24], 1);
  __syncthreads();
  int cntv = h[tid];
  int l = tid & 63, wv = tid >> 6;
  int s = cntv;
#pragma unroll
  for (int off = 1; off < 64; off <<= 1) { int t = __shfl_up(s, off); if (l >= off) s += t; }
  if (l == 63) wsum[wv] = s;
  __syncthreads();
  int woff = 0;
  for (int i = 0; i < wv; i++) woff += wsum[i];
  int lpre = woff + s - cntv;
  int d = (b << 8) + tid;
  if (d < N) {
    rp[d] = bb + lpre;
    dinv[d] = 1.0f / sqrtf((float)(cntv + 1));
  }
  __syncthreads();
  h[tid] = lpre;
  __syncthreads();
  for (int i = tid; i < n; i += 256) {
    unsigned r = eb[i];
    int dlow = r >> 24;
    int pos = bb + atomicAdd(&h[dlow], 1);
    col[pos] = (int)(r & 0xFFFFFFu);
  }
}

// convW [L][k][c] -> transposed fp16 planes [L][c][k]; Wlo UNSCALED residual.
__global__ __launch_bounds__(128) void k_prep_w(const float* __restrict__ convW, _Float16* __restrict__ Whi,
                                                _Float16* __restrict__ Wlo) {
  int lk = blockIdx.x;
  int l = lk >> 7, k = lk & 127, c = threadIdx.x;
  float x = convW[((size_t)l * 128 + k) * 128 + c];
  _Float16 hi = (_Float16)x;
  _Float16 lo = (_Float16)(x - (float)hi);
  size_t o = ((size_t)l * 128 + c) * 128 + k;
  Whi[o] = hi;
  Wlo[o] = lo;
}

// H'[i][c] = dinv[i] * relu(x[i] @ encW + encb)
__global__ __launch_bounds__(256) void k_encoder(const float* __restrict__ x, const float* __restrict__ W,
                                                 const float* __restrict__ b, const float* __restrict__ dinv,
                                                 _Float16* __restrict__ Hp, int N) {
  int node = blockIdx.x * 2 + (threadIdx.x >> 7);
  int c = threadIdx.x & 127;
  if (node >= N) return;
  const float* xr = x + (size_t)node * 16;
  float acc = b[c];
#pragma unroll
  for (int k = 0; k < 16; k++) acc = fmaf(xr[k], W[k * 128 + c], acc);
  Hp[(size_t)node * 128 + c] = (_Float16)(dinv[node] * fmaxf(acc, 0.0f));
}

// ---------------- fused layer ----------------
__global__ __launch_bounds__(512, 6) void k_layer(const _Float16* __restrict__ Hp, const int* __restrict__ rp,
                                                  const int* __restrict__ col, const float* __restrict__ dinv,
                                                  const _Float16* __restrict__ Whi, const _Float16* __restrict__ Wlo,
                                                  const float* __restrict__ bias, _Float16* __restrict__ Hn,
                                                  const float* __restrict__ decW, const float* __restrict__ decb,
                                                  float* __restrict__ out, int last, int N) {
  __shared__ __align__(16) ushort ldsM[128 * 128];  // 32 KB: 128 rows x 256B, XOR-swizzled
  __shared__ __align__(16) ushort ldsW[128 * 64];   // 16 KB: one W plane-half
  char* mB = reinterpret_cast<char*>(ldsM);
  char* wB = reinterpret_cast<char*>(ldsW);
  const int tid = threadIdx.x;
  const int row0 = blockIdx.x * 128;

  // ---- Phase 1: gather. 32 groups of 16 lanes; group owns 4 nodes (full row each).
  {
    int grp = tid >> 4, ln = tid & 15;
#pragma unroll
    for (int t = 0; t < 4; t++) {
      int lrow = grp * 4 + t;
      int d = row0 + lrow;
      int moff = (lrow * 256 + ln * 16) ^ ((lrow & 7) << 4);
      h8 z = {(_Float16)0, (_Float16)0, (_Float16)0, (_Float16)0,
              (_Float16)0, (_Float16)0, (_Float16)0, (_Float16)0};
      if (d < N) {
        h8 a0 = z, a1 = z, a2 = z, a3 = z;
        a0 += *reinterpret_cast<const h8*>(Hp + (size_t)d * 128 + ln * 8);  // self
        int e0 = rp[d], e1 = rp[d + 1];
        int i = e0;
        for (; i + 3 < e1; i += 4) {
          int s0 = col[i], s1 = col[i + 1], s2 = col[i + 2], s3 = col[i + 3];
          a0 += *reinterpret_cast<const h8*>(Hp + (size_t)s0 * 128 + ln * 8);
          a1 += *reinterpret_cast<const h8*>(Hp + (size_t)s1 * 128 + ln * 8);
          a2 += *reinterpret_cast<const h8*>(Hp + (size_t)s2 * 128 + ln * 8);
          a3 += *reinterpret_cast<const h8*>(Hp + (size_t)s3 * 128 + ln * 8);
        }
        if (i < e1)     a1 += *reinterpret_cast<const h8*>(Hp + (size_t)col[i] * 128 + ln * 8);
        if (i + 1 < e1) a2 += *reinterpret_cast<const h8*>(Hp + (size_t)col[i + 1] * 128 + ln * 8);
        if (i + 2 < e1) a3 += *reinterpret_cast<const h8*>(Hp + (size_t)col[i + 2] * 128 + ln * 8);
        h8 m;
#pragma unroll
        for (int j = 0; j < 8; j++) {
          float f = ((float)a0[j] + (float)a1[j]) + ((float)a2[j] + (float)a3[j]);
          m[j] = (_Float16)f;
        }
        *reinterpret_cast<h8*>(mB + moff) = m;
      } else {
        *reinterpret_cast<h8*>(mB + moff) = z;
      }
    }
  }
  __syncthreads();

  // ---- Phase 2: M @ (Whi + Wlo); W plane-half staged 16KB at a time; single acc.
  const int w = tid >> 6, l = tid & 63;
  const int wm = w >> 1, wn = w & 1;
  const int lr = l & 15, lg = l >> 4;
  f32x4 zero4 = {0.0f, 0.0f, 0.0f, 0.0f};
  f32x4 acc[2][4];
#pragma unroll
  for (int m = 0; m < 2; m++)
#pragma unroll
    for (int n = 0; n < 4; n++) acc[m][n] = zero4;

  for (int half = 0; half < 2; half++) {
#pragma unroll
    for (int plane = 0; plane < 2; plane++) {
      if (half | plane) __syncthreads();  // protect ldsW reuse
      const _Float16* Wp = plane ? Wlo : Whi;
#pragma unroll
      for (int i = 0; i < 2; i++) {
        int g = tid + i * 512;           // 0..1023
        int c = g >> 3, c16 = g & 7;
        uint4 v = *reinterpret_cast<const uint4*>(Wp + (size_t)c * 128 + half * 64 + c16 * 8);
        *reinterpret_cast<uint4*>(wB + ((c * 128 + c16 * 16) ^ ((c & 7) << 4))) = v;
      }
      __syncthreads();
#pragma unroll
      for (int ksl = 0; ksl < 2; ksl++) {
        int kb = (ksl * 32 + lg * 8) * 2;
        h8 ah[2];
#pragma unroll
        for (int m = 0; m < 2; m++) {
          int row = wm * 32 + m * 16 + lr;
          ah[m] = *reinterpret_cast<const h8*>(mB + ((row * 256 + half * 128 + kb) ^ ((row & 7) << 4)));
        }
        h8 wf[4];
#pragma unroll
        for (int n = 0; n < 4; n++) {
          int colr = wn * 64 + n * 16 + lr;
          wf[n] = *reinterpret_cast<const h8*>(wB + ((colr * 128 + kb) ^ ((colr & 7) << 4)));
        }
#pragma unroll
        for (int m = 0; m < 2; m++)
#pragma unroll
          for (int n = 0; n < 4; n++)
            acc[m][n] = __builtin_amdgcn_mfma_f32_16x16x32_f16(ah[m], wf[n], acc[m][n], 0, 0, 0);
      }
    }
  }

  // ---- Epilogue
  if (last) __syncthreads();  // all ldsM reads done before reuse
#pragma unroll
  for (int m = 0; m < 2; m++) {
    int lbase = wm * 32 + m * 16 + lg * 4;
#pragma unroll
    for (int r = 0; r < 4; r++) {
      int lrow = lbase + r;
      int grow = row0 + lrow;
      if (grow < N) {
        float dv = dinv[grow];
#pragma unroll
        for (int n = 0; n < 4; n++) {
          int colc = wn * 64 + n * 16 + lr;
          float h = fmaxf(fmaf(dv, acc[m][n][r], bias[colc]), 0.0f);
          if (!last) {
            Hn[(size_t)grow * 128 + colc] = (_Float16)(dv * h);
          } else {
            _Float16 hf = (_Float16)h;
            *reinterpret_cast<ushort*>(mB + ((lrow * 256 + colc * 2) ^ ((lrow & 7) << 4))) =
                *reinterpret_cast<ushort*>(&hf);
          }
        }
      }
    }
  }

  if (last) {
    __syncthreads();
    int grp = tid >> 4, ln = tid & 15;
#pragma unroll
    for (int t = 0; t < 4; t++) {
      int lrow = grp * 4 + t;
      int d = row0 + lrow;
      if (d < N) {
        h8 hv = *reinterpret_cast<const h8*>(mB + ((lrow * 256 + ln * 16) ^ ((lrow & 7) << 4)));
        float p0 = 0.f, p1 = 0.f, p2 = 0.f;
#pragma unroll
        for (int j = 0; j < 8; j++) {
          int c = ln * 8 + j;
          float o = (float)hv[j];
          p0 = fmaf(o, decW[c * 3 + 0], p0);
          p1 = fmaf(o, decW[c * 3 + 1], p1);
          p2 = fmaf(o, decW[c * 3 + 2], p2);
        }
#pragma unroll
        for (int off = 8; off > 0; off >>= 1) {
          p0 += __shfl_xor(p0, off);
          p1 += __shfl_xor(p1, off);
          p2 += __shfl_xor(p2, off);
        }
        if (ln == 0) {
          out[(size_t)d * 3 + 0] = p0 + decb[0];
          out[(size_t)d * 3 + 1] = p1 + decb[1];
          out[(size_t)d * 3 + 2] = p2 + decb[2];
        }
      }
    }
  }
}

extern "C" void kernel_launch(void* const* d_in, const int* in_sizes, int n_in,
                              void* d_out, int out_size, void* d_ws, size_t ws_size,
                              hipStream_t stream) {
  const float* x     = (const float*)d_in[0];
  const int*   ei    = (const int*)d_in[1];
  const float* encW  = (const float*)d_in[2];
  const float* encb  = (const float*)d_in[3];
  const float* convW = (const float*)d_in[4];
  const float* convb = (const float*)d_in[5];
  const float* decW  = (const float*)d_in[6];
  const float* decb  = (const float*)d_in[7];
  const int N = in_sizes[0] / 16;
  const int E = in_sizes[1] / 2;
  const int L = in_sizes[4] / (128 * 128);
  const int* src = ei;
  const int* dst = ei + E;
  const int NB = (N + 255) >> 8;

  char* p = (char*)d_ws;
  auto alloc = [&](size_t bytes) -> void* {
    void* q = (void*)p;
    p += (bytes + 255) & ~(size_t)255;
    return q;
  };
  int*       rp     = (int*)alloc((size_t)(N + 1) * 4);
  int*       bcnt   = (int*)alloc((size_t)NB * 4);
  int*       bbase  = (int*)alloc((size_t)NB * 4);
  float*     dinv   = (float*)alloc((size_t)N * 4);
  int*       colA   = (int*)alloc((size_t)E * 4);
  _Float16*  HA     = (_Float16*)alloc((size_t)N * 128 * 2);
  // HB aliases ebuf (ebuf dead after k_bfill; HB first written by layer 0).
  size_t hb_bytes   = (size_t)N * 128 * 2;
  size_t ebuf_bytes = (size_t)NB * BKT_CAP * 4;
  void*  hb_union   = alloc(hb_bytes > ebuf_bytes ? hb_bytes : ebuf_bytes);
  _Float16* HB      = (_Float16*)hb_union;
  unsigned* ebuf    = (unsigned*)hb_union;
  _Float16*  Whi    = (_Float16*)alloc((size_t)L * 128 * 128 * 2);
  _Float16*  Wlo    = (_Float16*)alloc((size_t)L * 128 * 128 * 2);

  hipMemsetAsync(bcnt, 0, (size_t)NB * 4, stream);
  k_bin<<<(E + 4095) / 4096, 256, 0, stream>>>(src, dst, bcnt, ebuf, E, NB);
  k_bscan<<<1, 512, 0, stream>>>(bcnt, bbase, rp, NB, N, E);
  k_bfill<<<NB, 256, 0, stream>>>(ebuf, bcnt, bbase, rp, dinv, colA, N);
  k_prep_w<<<L * 128, 128, 0, stream>>>(convW, Whi, Wlo);
  k_encoder<<<(N + 1) / 2, 256, 0, stream>>>(x, encW, encb, dinv, HA, N);
  int gblocks = (N + 127) / 128;
  _Float16* Hp = HA;
  _Float16* Hn = HB;
  for (int l = 0; l < L; l++) {
    int last = (l == L - 1) ? 1 : 0;
    k_layer<<<gblocks, 512, 0, stream>>>(Hp, rp, colA, dinv, Whi + (size_t)l * 128 * 128,
                                         Wlo + (size_t)l * 128 * 128, convb + l * 128, Hn,
                                         decW, decb, (float*)d_out, last, N);
    _Float16* t = Hp; Hp = Hn; Hn = t;
  }
}